// Round 6
// baseline (245.077 us; speedup 1.0000x reference)
//
#include <hip/hip_runtime.h>
#include <hip/hip_bf16.h>

// Problem: B=4, Tq=Tk=2048, E=1024, D=128, d=64. All inputs fp32, output fp32.
// Round 16: attn_split LDS diet + gload_lds staging. r15 evidence: KS=8 ran
// (WRITE 33.8MB) but occupancy stuck at 17% and dur ~46us -> residency is
// LDS-limited at 54.3KB/block, latency still exposed. Changes:
//  - K,V staged via global_load_lds w16 into LINEAR KP[64x128]/Vls[128x64]
//    shorts (16KB each), both-sides XOR swizzle colbyte^=((row&7)<<4)
//    (inverse-swz source + swz ds_read — same involution as gemm_proj).
//    Removes the 8xint4+8xds_write VGPR round-trip per thread per tile.
//  - P reuses KP's 16KB (4 waves x 2 halves x 16x64 bf16) after a barrier
//    confirming QK reads done; per-wave region, swizzled write/read.
//  - LDS 54.3 -> 32KB => 4 blocks/CU (VGPR-capped); KS=8 grid (1024 blocks)
//    now actually achieves 4/CU. 3 barriers/tile.
// T13 defer-max kept. gemm_proj/combine/tripwire unchanged from r15.

#define TQ 2048
#define TK 2048
#define EMB 1024
#define HD 128
#define MQ 8192  // B*Tq rows

typedef __attribute__((ext_vector_type(8))) short short8;   // 8 bf16 = 4 VGPR
typedef __attribute__((ext_vector_type(4))) float floatx4;  // MFMA acc

__device__ __forceinline__ unsigned short f2bf(float f) {  // RNE fp32->bf16
  union { float f; unsigned u; } v; v.f = f;
  unsigned r = v.u + 0x7fffu + ((v.u >> 16) & 1u);
  return (unsigned short)(r >> 16);
}
__device__ __forceinline__ float bf2f(unsigned short s) {
  union { unsigned u; float f; } v; v.u = ((unsigned)s) << 16;
  return v.f;
}

typedef const __attribute__((address_space(1))) unsigned int guint;
typedef __attribute__((address_space(3))) unsigned int luint;
__device__ __forceinline__ void gl16(const void* g, void* l) {
  __builtin_amdgcn_global_load_lds((guint*)g, (luint*)l, 16, 0, 0);
}

// ---------------------------------------------------------------- lambda ----
__global__ void lam_kernel(const float* __restrict__ lq1, const float* __restrict__ lk1,
                           const float* __restrict__ lq2, const float* __restrict__ lk2,
                           const float* __restrict__ linit, float* __restrict__ lam_out) {
  int j = threadIdx.x;  // 64 threads
  float s1 = lq1[j] * lk1[j] + lq1[j + 64] * lk1[j + 64];
  float s2 = lq2[j] * lk2[j] + lq2[j + 64] * lk2[j + 64];
  for (int off = 1; off < 64; off <<= 1) {
    s1 += __shfl_xor(s1, off);
    s2 += __shfl_xor(s2, off);
  }
  if (j == 0) lam_out[0] = __expf(s1) - __expf(s2) + linit[0];
}

// -------------------------------------------------- weight convert+transpose
__global__ __launch_bounds__(256) void cvtWT_kernel(
    const float* __restrict__ Wq, const float* __restrict__ Wk,
    const float* __restrict__ Wv, unsigned short* __restrict__ WqT,
    unsigned short* __restrict__ WkT, unsigned short* __restrict__ WvT) {
  const int g = blockIdx.y;
  const float* W = (g == 0) ? Wq : (g == 1) ? Wk : Wv;
  unsigned short* WT = (g == 0) ? WqT : (g == 1) ? WkT : WvT;
  int idx = blockIdx.x * 256 + threadIdx.x;  // [0, 131072)
  int n = idx >> 10, k = idx & 1023;
  WT[idx] = f2bf(W[(size_t)k * HD + n]);
}

// -------------------------------------------------------- MFMA projections ----
// grid (MQ/32, 3), 256 thr (4 waves). wave w: wm=w&1 -> rows 16wm..+16,
// wn=w>>1 -> cols 64wn..+64. Per K-step (BK=64): A fp32 32x64 (8KB, 8 chunks)
// + B^T bf16 128x64 (16KB, 16 chunks) staged via global_load_lds dwordx4,
// double-buffered; 8 MFMA/wave. g=0: qb*(0.125); g=1: kb; g=2: vbT^T.
__global__ __launch_bounds__(256) void gemm_proj_kernel(
    const float* __restrict__ x, const float* __restrict__ enc,
    const unsigned short* __restrict__ WqT, const unsigned short* __restrict__ WkT,
    const unsigned short* __restrict__ WvT,
    const float* __restrict__ bq, const float* __restrict__ bk,
    const float* __restrict__ bv,
    unsigned short* __restrict__ qb, unsigned short* __restrict__ kb,
    unsigned short* __restrict__ vbT) {
  __shared__ __align__(16) float Ab[2][32 * 64];             // 16 KB, linear (no pad)
  __shared__ __align__(16) unsigned short Bb[2][128 * 64];   // 32 KB, linear (no pad)
  const int t = threadIdx.x;
  const int w = t >> 6, lane = t & 63;
  const int lo = lane & 15, quad = lane >> 4;
  const int wm = w & 1, wn = w >> 1;
  const int g = blockIdx.y;
  const size_t m0 = (size_t)blockIdx.x * 32;
  const float* A = (g == 0) ? x : enc;
  const unsigned short* BT = (g == 0) ? WqT : (g == 1) ? WkT : WvT;
  const float* bias = (g == 0) ? bq : (g == 1) ? bk : bv;

  // Per-lane staging sources, pre-swizzled so linear LDS + swizzled ds_read
  // reconstructs the original element (involution: col_byte ^= ((row&7)<<4)).
  // A: 8 chunks of 1KB (4 rows x 256B); wave w owns chunks 2w, 2w+1.
  const float* gA[2];
  int ldsAoff[2];
#pragma unroll
  for (int j = 0; j < 2; ++j) {
    int c = 2 * w + j;
    int row = 4 * c + (lane >> 4);
    int colb = ((lane & 15) * 16) ^ ((row & 7) << 4);
    gA[j] = A + (m0 + row) * EMB + (colb >> 2);
    ldsAoff[j] = c * 1024;
  }
  // B: 16 chunks of 1KB (8 rows x 128B); wave w owns chunks 4w..4w+3.
  const unsigned short* gB[4];
  int ldsBoff[4];
#pragma unroll
  for (int j = 0; j < 4; ++j) {
    int c = 4 * w + j;
    int row = 8 * c + (lane >> 3);
    int colb = ((lane & 7) * 16) ^ ((row & 7) << 4);
    gB[j] = BT + (size_t)row * EMB + (colb >> 1);
    ldsBoff[j] = c * 1024;
  }

  floatx4 acc[4];
  const floatx4 zz = {0.f, 0.f, 0.f, 0.f};
#pragma unroll
  for (int i = 0; i < 4; ++i) acc[i] = zz;

  const int xr = (lo & 7) << 4;

  auto stage = [&](int kt, int bsel) {
#pragma unroll
    for (int j = 0; j < 2; ++j) gl16(gA[j] + kt, (char*)&Ab[bsel][0] + ldsAoff[j]);
#pragma unroll
    for (int j = 0; j < 4; ++j) gl16(gB[j] + kt, (char*)&Bb[bsel][0] + ldsBoff[j]);
  };

  auto compute = [&](int bsel) {
    const char* Arow = (const char*)&Ab[bsel][(16 * wm + lo) * 64];
    const char* Bbase = (const char*)&Bb[bsel][0];
#pragma unroll
    for (int ks = 0; ks < 2; ++ks) {
      int a0 = (ks * 128 + quad * 32) ^ xr;
      float4 fa = *(const float4*)(Arow + a0);         // orig cols ks*32+q8 .. +3
      float4 fb = *(const float4*)(Arow + (a0 ^ 16));  // orig cols ks*32+q8+4 .. +7
      short8 af;
      af[0] = (short)f2bf(fa.x); af[1] = (short)f2bf(fa.y);
      af[2] = (short)f2bf(fa.z); af[3] = (short)f2bf(fa.w);
      af[4] = (short)f2bf(fb.x); af[5] = (short)f2bf(fb.y);
      af[6] = (short)f2bf(fb.z); af[7] = (short)f2bf(fb.w);
      int b0 = (ks * 64 + quad * 16) ^ xr;
#pragma unroll
      for (int nt = 0; nt < 4; ++nt) {
        int row = wn * 64 + nt * 16 + lo;
        short8 bfr = *(const short8*)(Bbase + row * 128 + b0);
        acc[nt] = __builtin_amdgcn_mfma_f32_16x16x32_bf16(af, bfr, acc[nt], 0, 0, 0);
      }
    }
  };

  // prologue: stage K-tile 0 into buf0 (syncthreads drains vmcnt+lgkmcnt)
  stage(0, 0);
  __syncthreads();

  // 2-phase pipeline, unrolled 2-deep -> static buffer indices
  for (int kt = 0; kt < EMB; kt += 128) {
    stage(kt + 64, 1);          // prefetch next tile (kt+64 <= 960, always valid)
    compute(0);                 // consume tile kt
    __syncthreads();            // drains: buf1 loads done, buf0 reads done
    if (kt + 128 < EMB) stage(kt + 128, 0);
    compute(1);                 // consume tile kt+64
    __syncthreads();
  }

  // epilogue: rows m0+16wm+quad*4+r, cols 64wn+nt*16+lo
  const int mrow = 16 * wm + quad * 4;
  if (g < 2) {
    unsigned short* Y = (g == 0) ? qb : kb;
    const float sc = (g == 0) ? 0.125f : 1.0f;
#pragma unroll
    for (int nt = 0; nt < 4; ++nt) {
      float bn = bias[wn * 64 + nt * 16 + lo];
#pragma unroll
      for (int r = 0; r < 4; ++r)
        Y[(m0 + mrow + r) * HD + wn * 64 + nt * 16 + lo] = f2bf((acc[nt][r] + bn) * sc);
    }
  } else {
#pragma unroll
    for (int nt = 0; nt < 4; ++nt) {
      float bn = bias[wn * 64 + nt * 16 + lo];
      unsigned long long pk = 0;
#pragma unroll
      for (int r = 0; r < 4; ++r)
        pk |= (unsigned long long)f2bf(acc[nt][r] + bn) << (16 * r);
      *(unsigned long long*)&vbT[(size_t)(wn * 64 + nt * 16 + lo) * MQ + m0 + mrow] = pk;
    }
  }
}

// ---------------------------------------------------- attention (key-split) ----
// Round 16: gload_lds K/V staging into linear swizzled tiles; P reuses KP.
// LDS = 32KB -> 4 blocks/CU. Per tile: stage -> bar -> QK -> bar -> P-write
// (own wave region) -> PV -> bar. T13 defer-max kept.
__global__ __launch_bounds__(256) void attn_split_kernel(
    const unsigned short* __restrict__ qb, const unsigned short* __restrict__ kb,
    const unsigned short* __restrict__ vbT,
    unsigned short* __restrict__ pO1, unsigned short* __restrict__ pO2,
    float4* __restrict__ pstats, int nkeys) {
  __shared__ __align__(16) unsigned short KP[64 * 128];   // K tile (16KB); P after QK
  __shared__ __align__(16) unsigned short Vls[128 * 64];  // V^T tile (16KB)

  const int t = threadIdx.x;
  const int w = t >> 6;
  const int lane = t & 63;
  const int lo = lane & 15;
  const int quad = lane >> 4;
  const int q8 = quad * 8;
  const int xr2 = (lo & 7) << 4;         // read-side swizzle (row&7 == lo&7)
  const int b = blockIdx.y;
  const int q0 = blockIdx.x * 64;
  const int ksp = blockIdx.z;
  const int kt0 = ksp * nkeys;
  const size_t kbase = (size_t)b * TK;

  const size_t qrow = (size_t)b * TQ + q0 + w * 16 + lo;
  short8 qf[2][2];
#pragma unroll
  for (int half = 0; half < 2; ++half)
#pragma unroll
    for (int ks = 0; ks < 2; ++ks)
      qf[half][ks] = *(const short8*)&qb[qrow * HD + half * 64 + ks * 32 + q8];

  // Staging descriptors: wave w owns 1KB wave-chunks {w, w+4, w+8, w+12} of
  // each 16KB tile. gl16 dest = wave-uniform base + lane*16 (linear). Source
  // is inverse-swizzled so swizzled ds_read reconstructs logical elements.
  const char* kSrc[4];
  const char* vSrc[4];
  int ldsOff[4];
#pragma unroll
  for (int j = 0; j < 4; ++j) {
    int W = w + 4 * j;
    int c = W * 64 + lane;
    // K: [64][128] shorts, 16 chunks/row. key=c>>4, colchunk=c&15.
    int key = c >> 4;
    int kcol = ((c & 15) * 8) ^ ((key & 7) << 3);  // shorts
    kSrc[j] = (const char*)&kb[(kbase + key) * HD + kcol];
    // V: [128][64] shorts, 8 chunks/row. f=c>>3, colchunk=c&7.
    int f = c >> 3;
    int vcol = ((c & 7) * 8) ^ ((f & 7) << 3);     // shorts
    vSrc[j] = (const char*)&vbT[(size_t)f * MQ + kbase + vcol];
    ldsOff[j] = W * 1024;
  }

  floatx4 o1[8], o2[8];
  const floatx4 zz = {0.f, 0.f, 0.f, 0.f};
#pragma unroll
  for (int i = 0; i < 8; ++i) { o1[i] = zz; o2[i] = zz; }
  float m1[4], l1[4], m2[4], l2[4];
#pragma unroll
  for (int r = 0; r < 4; ++r) { m1[r] = m2[r] = -1e30f; l1[r] = l2[r] = 0.f; }

  for (int kt = kt0; kt < kt0 + nkeys; kt += 64) {
#pragma unroll
    for (int j = 0; j < 4; ++j) {
      gl16(kSrc[j] + (size_t)kt * 256, (char*)KP + ldsOff[j]);   // K row adv 256B/key-tile
      gl16(vSrc[j] + (size_t)kt * 2, (char*)Vls + ldsOff[j]);    // V col adv 2B/key
    }
    __syncthreads();  // drains gl16 -> K,V visible

    floatx4 s1[4], s2[4];
#pragma unroll
    for (int i = 0; i < 4; ++i) { s1[i] = zz; s2[i] = zz; }
    const char* Kb = (const char*)KP;
#pragma unroll
    for (int ks = 0; ks < 2; ++ks)
#pragma unroll
      for (int nt = 0; nt < 4; ++nt) {
        int rb = (nt * 16 + lo) * 256;
        int cb = (ks * 64 + quad * 16) ^ xr2;
        short8 kf1 = *(const short8*)(Kb + rb + cb);
        short8 kf2 = *(const short8*)(Kb + rb + (cb ^ 128));  // half 1 at +128B
        s1[nt] = __builtin_amdgcn_mfma_f32_16x16x32_bf16(qf[0][ks], kf1, s1[nt], 0, 0, 0);
        s2[nt] = __builtin_amdgcn_mfma_f32_16x16x32_bf16(qf[1][ks], kf2, s2[nt], 0, 0, 0);
      }
    __syncthreads();  // all waves done reading K -> safe to overwrite with P

    // per-row tile maxes
    float tm1[4], tm2[4];
#pragma unroll
    for (int r = 0; r < 4; ++r) {
      float a = fmaxf(fmaxf(s1[0][r], s1[1][r]), fmaxf(s1[2][r], s1[3][r]));
      float c2 = fmaxf(fmaxf(s2[0][r], s2[1][r]), fmaxf(s2[2][r], s2[3][r]));
#pragma unroll
      for (int o = 1; o < 16; o <<= 1) {
        a = fmaxf(a, __shfl_xor(a, o));
        c2 = fmaxf(c2, __shfl_xor(c2, o));
      }
      tm1[r] = a; tm2[r] = c2;
    }
    // T13 defer-max
    bool grow = false;
#pragma unroll
    for (int r = 0; r < 4; ++r)
      grow = grow || (tm1[r] > m1[r] + 5.f) || (tm2[r] > m2[r] + 5.f);
    if (__any(grow)) {
#pragma unroll
      for (int r = 0; r < 4; ++r) {
        float mn1 = fmaxf(m1[r], tm1[r]), mn2 = fmaxf(m2[r], tm2[r]);
        float al1 = __expf(m1[r] - mn1), al2 = __expf(m2[r] - mn2);
        m1[r] = mn1; m2[r] = mn2;
        l1[r] *= al1; l2[r] *= al2;
#pragma unroll
        for (int nt = 0; nt < 8; ++nt) { o1[nt][r] *= al1; o2[nt][r] *= al2; }
      }
    }
    // P = exp(s - m), write into own wave's 4KB of KP (swizzled both sides)
    char* Pb = (char*)KP + w * 4096;
#pragma unroll
    for (int r = 0; r < 4; ++r) {
      float ls1 = 0.f, ls2 = 0.f;
      int rr = quad * 4 + r;
      int rbase = rr * 128;
      int rx = (rr & 7) << 4;
#pragma unroll
      for (int nt = 0; nt < 4; ++nt) {
        float p1 = __expf(s1[nt][r] - m1[r]);
        float p2 = __expf(s2[nt][r] - m2[r]);
        ls1 += p1; ls2 += p2;
        int pb = rbase + (((nt * 16 + lo) * 2) ^ rx);
        *(unsigned short*)(Pb + pb) = f2bf(p1);
        *(unsigned short*)(Pb + pb + 2048) = f2bf(p2);
      }
#pragma unroll
      for (int o = 1; o < 16; o <<= 1) {
        ls1 += __shfl_xor(ls1, o);
        ls2 += __shfl_xor(ls2, o);
      }
      l1[r] += ls1;
      l2[r] += ls2;
    }

    const char* Vb = (const char*)Vls;
#pragma unroll
    for (int ks = 0; ks < 2; ++ks) {
      int cb = (ks * 64 + quad * 16) ^ xr2;
      short8 p1 = *(const short8*)(Pb + lo * 128 + cb);
      short8 p2 = *(const short8*)(Pb + 2048 + lo * 128 + cb);
#pragma unroll
      for (int nt = 0; nt < 8; ++nt) {
        short8 vf = *(const short8*)(Vb + (nt * 16 + lo) * 128 + cb);
        o1[nt] = __builtin_amdgcn_mfma_f32_16x16x32_bf16(p1, vf, o1[nt], 0, 0, 0);
        o2[nt] = __builtin_amdgcn_mfma_f32_16x16x32_bf16(p2, vf, o2[nt], 0, 0, 0);
      }
    }
    __syncthreads();  // P/V reads done -> safe to restage
  }

#pragma unroll
  for (int r = 0; r < 4; ++r) {
    int rowb = q0 + w * 16 + quad * 4 + r;
    size_t idx = ((size_t)(ksp * 4 + b)) * TQ + rowb;
    if (lo == 0) pstats[idx] = make_float4(m1[r], l1[r], m2[r], l2[r]);
#pragma unroll
    for (int nt = 0; nt < 8; ++nt) {
      pO1[idx * HD + nt * 16 + lo] = f2bf(o1[nt][r]);
      pO2[idx * HD + nt * 16 + lo] = f2bf(o2[nt][r]);
    }
  }
}

// ---------------------------------------------------------------- combine ----
// Stat arrays sized for KS up to 8.
__global__ __launch_bounds__(256) void attn_combine_kernel(
    const unsigned short* __restrict__ pO1, const unsigned short* __restrict__ pO2,
    const float4* __restrict__ pstats, const float* __restrict__ lam_ptr,
    float* __restrict__ out, int ksn) {
  const int t = threadIdx.x;
  const int b = blockIdx.y;
  const int row = blockIdx.x * 16 + (t >> 4);
  const int dg = t & 15;

  float m1s[8], l1s[8], m2s[8], l2s[8];
  float M1 = -1e30f, M2 = -1e30f;
  for (int s = 0; s < ksn; ++s) {
    float4 f4 = pstats[((size_t)(s * 4 + b)) * TQ + row];
    m1s[s] = f4.x; l1s[s] = f4.y; m2s[s] = f4.z; l2s[s] = f4.w;
    M1 = fmaxf(M1, f4.x); M2 = fmaxf(M2, f4.z);
  }
  float L1 = 0.f, L2 = 0.f, e1[8], e2[8];
  for (int s = 0; s < ksn; ++s) {
    e1[s] = __expf(m1s[s] - M1); e2[s] = __expf(m2s[s] - M2);
    L1 += l1s[s] * e1[s]; L2 += l2s[s] * e2[s];
  }
  float a1[8], a2[8];
#pragma unroll
  for (int j = 0; j < 8; ++j) { a1[j] = 0.f; a2[j] = 0.f; }
  for (int s = 0; s < ksn; ++s) {
    size_t base = (((size_t)(s * 4 + b)) * TQ + row) * HD + dg * 8;
    int4 r1 = *(const int4*)&pO1[base];
    int4 r2 = *(const int4*)&pO2[base];
    const unsigned short* u1 = (const unsigned short*)&r1;
    const unsigned short* u2 = (const unsigned short*)&r2;
#pragma unroll
    for (int j = 0; j < 8; ++j) {
      a1[j] += bf2f(u1[j]) * e1[s];
      a2[j] += bf2f(u2[j]) * e2[s];
    }
  }
  const float i1 = 1.f / L1;
  const float i2 = lam_ptr[0] / L2;
  float4* op = (float4*)&out[((size_t)b * TQ + row) * HD + dg * 8];
  op[0] = make_float4(a1[0] * i1 - a2[0] * i2, a1[1] * i1 - a2[1] * i2,
                      a1[2] * i1 - a2[2] * i2, a1[3] * i1 - a2[3] * i2);
  op[1] = make_float4(a1[4] * i1 - a2[4] * i2, a1[5] * i1 - a2[5] * i2,
                      a1[6] * i1 - a2[6] * i2, a1[7] * i1 - a2[7] * i2);
}

// --------------------------------------------------------------- tripwire ----
__global__ __launch_bounds__(256) void attn_check_kernel(
    const unsigned short* __restrict__ qb, const unsigned short* __restrict__ kb,
    const unsigned short* __restrict__ vbT, const float* __restrict__ lamp,
    float* __restrict__ out) {
  __shared__ float qsh[HD];
  __shared__ float sred[4][4];
  const int t = threadIdx.x;
  const int w = t >> 6, lane = t & 63;
  const int bb = blockIdx.x & 3;
  const int q = (int)((blockIdx.x * 997u + 13u) & 2047u);
  const int dc = (int)((blockIdx.x * 37u + 5u) & 127u);

  const unsigned short* qr = &qb[((size_t)bb * TQ + q) * HD];
  if (t < HD) qsh[t] = bf2f(qr[t]);
  __syncthreads();

  float mx1 = -1e30f, mx2 = -1e30f;
  for (int it = 0; it < 8; ++it) {
    int key = t + 256 * it;
    const unsigned* kr = (const unsigned*)&kb[((size_t)bb * TK + key) * HD];
    float s1 = 0.f, s2 = 0.f;
#pragma unroll 8
    for (int du = 0; du < 32; ++du) {
      unsigned u1 = kr[du], u2 = kr[32 + du];
      s1 += qsh[2 * du] * bf2f((unsigned short)u1) +
            qsh[2 * du + 1] * bf2f((unsigned short)(u1 >> 16));
      s2 += qsh[64 + 2 * du] * bf2f((unsigned short)u2) +
            qsh[64 + 2 * du + 1] * bf2f((unsigned short)(u2 >> 16));
    }
    mx1 = fmaxf(mx1, s1); mx2 = fmaxf(mx2, s2);
  }
  for (int o = 1; o < 64; o <<= 1) {
    mx1 = fmaxf(mx1, __shfl_xor(mx1, o));
    mx2 = fmaxf(mx2, __shfl_xor(mx2, o));
  }
  if (lane == 0) { sred[0][w] = mx1; sred[1][w] = mx2; }
  __syncthreads();
  mx1 = fmaxf(fmaxf(sred[0][0], sred[0][1]), fmaxf(sred[0][2], sred[0][3]));
  mx2 = fmaxf(fmaxf(sred[1][0], sred[1][1]), fmaxf(sred[1][2], sred[1][3]));
  __syncthreads();

  float l1 = 0.f, l2 = 0.f, o1 = 0.f, o2 = 0.f;
  for (int it = 0; it < 8; ++it) {
    int key = t + 256 * it;
    const unsigned* kr = (const unsigned*)&kb[((size_t)bb * TK + key) * HD];
    float s1 = 0.f, s2 = 0.f;
#pragma unroll 8
    for (int du = 0; du < 32; ++du) {
      unsigned u1 = kr[du], u2 = kr[32 + du];
      s1 += qsh[2 * du] * bf2f((unsigned short)u1) +
            qsh[2 * du + 1] * bf2f((unsigned short)(u1 >> 16));
      s2 += qsh[64 + 2 * du] * bf2f((unsigned short)u2) +
            qsh[64 + 2 * du + 1] * bf2f((unsigned short)(u2 >> 16));
    }
    float p1 = __expf(s1 - mx1), p2 = __expf(s2 - mx2);
    float v = bf2f(vbT[(size_t)dc * MQ + bb * TK + key]);
    l1 += p1; l2 += p2; o1 += p1 * v; o2 += p2 * v;
  }
  for (int o = 1; o < 64; o <<= 1) {
    l1 += __shfl_xor(l1, o); l2 += __shfl_xor(l2, o);
    o1 += __shfl_xor(o1, o); o2 += __shfl_xor(o2, o);
  }
  if (lane == 0) { sred[0][w] = l1; sred[1][w] = l2; sred[2][w] = o1; sred[3][w] = o2; }
  __syncthreads();
  if (t == 0) {
    l1 = sred[0][0] + sred[0][1] + sred[0][2] + sred[0][3];
    l2 = sred[1][0] + sred[1][1] + sred[1][2] + sred[1][3];
    o1 = sred[2][0] + sred[2][1] + sred[2][2] + sred[2][3];
    o2 = sred[3][0] + sred[3][1] + sred[3][2] + sred[3][3];
    float res = o1 / l1 - lamp[0] * (o2 / l2);
    float got = out[((size_t)bb * TQ + q) * HD + dc];
    if (!(fabsf(res - got) <= 0.02f)) out[0] = 1.0e7f;
  }
}

extern "C" void kernel_launch(void* const* d_in, const int* in_sizes, int n_in,
                              void* d_out, int out_size, void* d_ws, size_t ws_size,
                              hipStream_t stream) {
  const float* x    = (const float*)d_in[0];
  const float* enc  = (const float*)d_in[1];
  const float* Wq   = (const float*)d_in[2];
  const float* bq   = (const float*)d_in[3];
  const float* Wk   = (const float*)d_in[4];
  const float* bk   = (const float*)d_in[5];
  const float* Wv   = (const float*)d_in[6];
  const float* bv   = (const float*)d_in[7];
  const float* lq1  = (const float*)d_in[8];
  const float* lk1  = (const float*)d_in[9];
  const float* lq2  = (const float*)d_in[10];
  const float* lk2  = (const float*)d_in[11];
  const float* lini = (const float*)d_in[12];
  float* out = (float*)d_out;

  char* p = (char*)d_ws;
  float* lam = (float*)p;                       p += 256;
  unsigned short* qb  = (unsigned short*)p;     p += (size_t)MQ * HD * 2;
  unsigned short* kb  = (unsigned short*)p;     p += (size_t)MQ * HD * 2;
  unsigned short* vbT = (unsigned short*)p;     p += (size_t)MQ * HD * 2;  // [128][8192]
  unsigned short* WqT = (unsigned short*)p;     p += (size_t)EMB * HD * 2;
  unsigned short* WkT = (unsigned short*)p;     p += (size_t)EMB * HD * 2;
  unsigned short* WvT = (unsigned short*)p;     p += (size_t)EMB * HD * 2;
  const size_t base_need = (size_t)(p - (char*)d_ws);

  const size_t per_ks = (size_t)4 * TQ * 16 + 2ull * 4 * TQ * HD * 2;
  int KS = 8;
  while (KS > 1 && base_need + (size_t)KS * per_ks > ws_size) KS >>= 1;

  float4* pstats = (float4*)p;                  p += (size_t)KS * 4 * TQ * 16;
  unsigned short* pO1 = (unsigned short*)p;     p += (size_t)KS * 4 * TQ * HD * 2;
  unsigned short* pO2 = (unsigned short*)p;

  hipLaunchKernelGGL(lam_kernel, dim3(1), dim3(64), 0, stream,
                     lq1, lk1, lq2, lk2, lini, lam);
  hipLaunchKernelGGL(cvtWT_kernel, dim3(512, 3), dim3(256), 0, stream,
                     Wq, Wk, Wv, WqT, WkT, WvT);
  hipLaunchKernelGGL(gemm_proj_kernel, dim3(MQ / 32, 3), dim3(256), 0, stream,
                     x, enc, WqT, WkT, WvT, bq, bk, bv, qb, kb, vbT);
  hipLaunchKernelGGL(attn_split_kernel, dim3(TQ / 64, 4, KS), dim3(256), 0, stream,
                     qb, kb, vbT, pO1, pO2, pstats, TK / KS);
  hipLaunchKernelGGL(attn_combine_kernel, dim3(TQ / 16, 4), dim3(256), 0, stream,
                     pO1, pO2, pstats, lam, out, KS);
  hipLaunchKernelGGL(attn_check_kernel, dim3(128), dim3(256), 0, stream,
                     qb, kb, vbT, lam, out);
}

// Round 7
// 215.410 us; speedup vs baseline: 1.1377x; 1.1377x over previous
//
#include <hip/hip_runtime.h>
#include <hip/hip_bf16.h>

// Problem: B=4, Tq=Tk=2048, E=1024, D=128, d=64. All inputs fp32, output fp32.
// Round 17: bank the best-known config. r16 post-mortem: VGPR 128->132 crossed
// the measured occupancy cliff (waves/SIMD halve past 128) -> 85us; r15's KS=8
// showed identical per-tile throughput to r11 -> 3rd block/CU never resident
// (runtime LDS reserve above 54.3KB x3). Every restructuring (r12-r16) lost to
// r11's 44us attn_split. This round:
//  - attn_split: r11 staging + T13 defer-max (measured VGPR=128 in r15),
//    KS=4 (8 tiles/block: rescale fires ~tile0 only; half the partial traffic
//    of KS=8).
//  - lam_kernel folded into cvtWT (blockIdx.y==3) -> one fewer launch.
// gemm_proj (r11 2-phase gload_lds pipeline) unchanged. Tripwire unchanged.

#define TQ 2048
#define TK 2048
#define EMB 1024
#define HD 128
#define MQ 8192  // B*Tq rows

typedef __attribute__((ext_vector_type(8))) short short8;   // 8 bf16 = 4 VGPR
typedef __attribute__((ext_vector_type(4))) float floatx4;  // MFMA acc

__device__ __forceinline__ unsigned short f2bf(float f) {  // RNE fp32->bf16
  union { float f; unsigned u; } v; v.f = f;
  unsigned r = v.u + 0x7fffu + ((v.u >> 16) & 1u);
  return (unsigned short)(r >> 16);
}
__device__ __forceinline__ float bf2f(unsigned short s) {
  union { unsigned u; float f; } v; v.u = ((unsigned)s) << 16;
  return v.f;
}

typedef const __attribute__((address_space(1))) unsigned int guint;
typedef __attribute__((address_space(3))) unsigned int luint;
__device__ __forceinline__ void gl16(const void* g, void* l) {
  __builtin_amdgcn_global_load_lds((guint*)g, (luint*)l, 16, 0, 0);
}

// ------------------------------------- weight convert+transpose (+ lambda) ----
__global__ __launch_bounds__(256) void cvtWT_kernel(
    const float* __restrict__ Wq, const float* __restrict__ Wk,
    const float* __restrict__ Wv, unsigned short* __restrict__ WqT,
    unsigned short* __restrict__ WkT, unsigned short* __restrict__ WvT,
    const float* __restrict__ lq1, const float* __restrict__ lk1,
    const float* __restrict__ lq2, const float* __restrict__ lk2,
    const float* __restrict__ linit, float* __restrict__ lam_out) {
  const int g = blockIdx.y;
  if (g == 3) {  // lambda: one block, first wave
    if (blockIdx.x == 0 && threadIdx.x < 64) {
      int j = threadIdx.x;
      float s1 = lq1[j] * lk1[j] + lq1[j + 64] * lk1[j + 64];
      float s2 = lq2[j] * lk2[j] + lq2[j + 64] * lk2[j + 64];
      for (int off = 1; off < 64; off <<= 1) {
        s1 += __shfl_xor(s1, off);
        s2 += __shfl_xor(s2, off);
      }
      if (j == 0) lam_out[0] = __expf(s1) - __expf(s2) + linit[0];
    }
    return;
  }
  const float* W = (g == 0) ? Wq : (g == 1) ? Wk : Wv;
  unsigned short* WT = (g == 0) ? WqT : (g == 1) ? WkT : WvT;
  int idx = blockIdx.x * 256 + threadIdx.x;  // [0, 131072)
  int n = idx >> 10, k = idx & 1023;
  WT[idx] = f2bf(W[(size_t)k * HD + n]);
}

// -------------------------------------------------------- MFMA projections ----
// grid (MQ/32, 3), 256 thr (4 waves). wave w: wm=w&1 -> rows 16wm..+16,
// wn=w>>1 -> cols 64wn..+64. Per K-step (BK=64): A fp32 32x64 (8KB, 8 chunks)
// + B^T bf16 128x64 (16KB, 16 chunks) staged via global_load_lds dwordx4,
// double-buffered; 8 MFMA/wave. g=0: qb*(0.125); g=1: kb; g=2: vbT^T.
__global__ __launch_bounds__(256) void gemm_proj_kernel(
    const float* __restrict__ x, const float* __restrict__ enc,
    const unsigned short* __restrict__ WqT, const unsigned short* __restrict__ WkT,
    const unsigned short* __restrict__ WvT,
    const float* __restrict__ bq, const float* __restrict__ bk,
    const float* __restrict__ bv,
    unsigned short* __restrict__ qb, unsigned short* __restrict__ kb,
    unsigned short* __restrict__ vbT) {
  __shared__ __align__(16) float Ab[2][32 * 64];             // 16 KB, linear (no pad)
  __shared__ __align__(16) unsigned short Bb[2][128 * 64];   // 32 KB, linear (no pad)
  const int t = threadIdx.x;
  const int w = t >> 6, lane = t & 63;
  const int lo = lane & 15, quad = lane >> 4;
  const int wm = w & 1, wn = w >> 1;
  const int g = blockIdx.y;
  const size_t m0 = (size_t)blockIdx.x * 32;
  const float* A = (g == 0) ? x : enc;
  const unsigned short* BT = (g == 0) ? WqT : (g == 1) ? WkT : WvT;
  const float* bias = (g == 0) ? bq : (g == 1) ? bk : bv;

  // Per-lane staging sources, pre-swizzled so linear LDS + swizzled ds_read
  // reconstructs the original element (involution: col_byte ^= ((row&7)<<4)).
  // A: 8 chunks of 1KB (4 rows x 256B); wave w owns chunks 2w, 2w+1.
  const float* gA[2];
  int ldsAoff[2];
#pragma unroll
  for (int j = 0; j < 2; ++j) {
    int c = 2 * w + j;
    int row = 4 * c + (lane >> 4);
    int colb = ((lane & 15) * 16) ^ ((row & 7) << 4);
    gA[j] = A + (m0 + row) * EMB + (colb >> 2);
    ldsAoff[j] = c * 1024;
  }
  // B: 16 chunks of 1KB (8 rows x 128B); wave w owns chunks 4w..4w+3.
  const unsigned short* gB[4];
  int ldsBoff[4];
#pragma unroll
  for (int j = 0; j < 4; ++j) {
    int c = 4 * w + j;
    int row = 8 * c + (lane >> 3);
    int colb = ((lane & 7) * 16) ^ ((row & 7) << 4);
    gB[j] = BT + (size_t)row * EMB + (colb >> 1);
    ldsBoff[j] = c * 1024;
  }

  floatx4 acc[4];
  const floatx4 zz = {0.f, 0.f, 0.f, 0.f};
#pragma unroll
  for (int i = 0; i < 4; ++i) acc[i] = zz;

  const int xr = (lo & 7) << 4;

  auto stage = [&](int kt, int bsel) {
#pragma unroll
    for (int j = 0; j < 2; ++j) gl16(gA[j] + kt, (char*)&Ab[bsel][0] + ldsAoff[j]);
#pragma unroll
    for (int j = 0; j < 4; ++j) gl16(gB[j] + kt, (char*)&Bb[bsel][0] + ldsBoff[j]);
  };

  auto compute = [&](int bsel) {
    const char* Arow = (const char*)&Ab[bsel][(16 * wm + lo) * 64];
    const char* Bbase = (const char*)&Bb[bsel][0];
#pragma unroll
    for (int ks = 0; ks < 2; ++ks) {
      int a0 = (ks * 128 + quad * 32) ^ xr;
      float4 fa = *(const float4*)(Arow + a0);         // orig cols ks*32+q8 .. +3
      float4 fb = *(const float4*)(Arow + (a0 ^ 16));  // orig cols ks*32+q8+4 .. +7
      short8 af;
      af[0] = (short)f2bf(fa.x); af[1] = (short)f2bf(fa.y);
      af[2] = (short)f2bf(fa.z); af[3] = (short)f2bf(fa.w);
      af[4] = (short)f2bf(fb.x); af[5] = (short)f2bf(fb.y);
      af[6] = (short)f2bf(fb.z); af[7] = (short)f2bf(fb.w);
      int b0 = (ks * 64 + quad * 16) ^ xr;
#pragma unroll
      for (int nt = 0; nt < 4; ++nt) {
        int row = wn * 64 + nt * 16 + lo;
        short8 bfr = *(const short8*)(Bbase + row * 128 + b0);
        acc[nt] = __builtin_amdgcn_mfma_f32_16x16x32_bf16(af, bfr, acc[nt], 0, 0, 0);
      }
    }
  };

  // prologue: stage K-tile 0 into buf0 (syncthreads drains vmcnt+lgkmcnt)
  stage(0, 0);
  __syncthreads();

  // 2-phase pipeline, unrolled 2-deep -> static buffer indices
  for (int kt = 0; kt < EMB; kt += 128) {
    stage(kt + 64, 1);          // prefetch next tile (kt+64 <= 960, always valid)
    compute(0);                 // consume tile kt
    __syncthreads();            // drains: buf1 loads done, buf0 reads done
    if (kt + 128 < EMB) stage(kt + 128, 0);
    compute(1);                 // consume tile kt+64
    __syncthreads();
  }

  // epilogue: rows m0+16wm+quad*4+r, cols 64wn+nt*16+lo
  const int mrow = 16 * wm + quad * 4;
  if (g < 2) {
    unsigned short* Y = (g == 0) ? qb : kb;
    const float sc = (g == 0) ? 0.125f : 1.0f;
#pragma unroll
    for (int nt = 0; nt < 4; ++nt) {
      float bn = bias[wn * 64 + nt * 16 + lo];
#pragma unroll
      for (int r = 0; r < 4; ++r)
        Y[(m0 + mrow + r) * HD + wn * 64 + nt * 16 + lo] = f2bf((acc[nt][r] + bn) * sc);
    }
  } else {
#pragma unroll
    for (int nt = 0; nt < 4; ++nt) {
      float bn = bias[wn * 64 + nt * 16 + lo];
      unsigned long long pk = 0;
#pragma unroll
      for (int r = 0; r < 4; ++r)
        pk |= (unsigned long long)f2bf(acc[nt][r] + bn) << (16 * r);
      *(unsigned long long*)&vbT[(size_t)(wn * 64 + nt * 16 + lo) * MQ + m0 + mrow] = pk;
    }
  }
}

// ---------------------------------------------------- attention (key-split) ----
// Round 17: r11 single-buffered staging (VGPR=128, no spill) + T13 defer-max.
// KS=4 -> nkeys=512 -> 8 K-tiles per block, 512 blocks.
__global__ __launch_bounds__(256) void attn_split_kernel(
    const unsigned short* __restrict__ qb, const unsigned short* __restrict__ kb,
    const unsigned short* __restrict__ vbT,
    unsigned short* __restrict__ pO1, unsigned short* __restrict__ pO2,
    float4* __restrict__ pstats, int nkeys) {
  __shared__ __align__(16) unsigned short Kls[64][136];      // 17.4 KB
  __shared__ __align__(16) unsigned short Vt[128][72];       // 18.4 KB
  __shared__ __align__(16) unsigned short Pls[4][2][16][72]; // 18.4 KB

  const int t = threadIdx.x;
  const int w = t >> 6;
  const int lane = t & 63;
  const int lo = lane & 15;
  const int quad = lane >> 4;
  const int q8 = quad * 8;
  const int b = blockIdx.y;
  const int q0 = blockIdx.x * 64;
  const int ksp = blockIdx.z;
  const int kt0 = ksp * nkeys;
  const size_t kbase = (size_t)b * TK;

  const size_t qrow = (size_t)b * TQ + q0 + w * 16 + lo;
  short8 qf[2][2];
#pragma unroll
  for (int half = 0; half < 2; ++half)
#pragma unroll
    for (int ks = 0; ks < 2; ++ks)
      qf[half][ks] = *(const short8*)&qb[qrow * HD + half * 64 + ks * 32 + q8];

  floatx4 o1[8], o2[8];
  const floatx4 zz = {0.f, 0.f, 0.f, 0.f};
#pragma unroll
  for (int i = 0; i < 8; ++i) { o1[i] = zz; o2[i] = zz; }
  float m1[4], l1[4], m2[4], l2[4];
#pragma unroll
  for (int r = 0; r < 4; ++r) { m1[r] = m2[r] = -1e30f; l1[r] = l2[r] = 0.f; }

  for (int kt = kt0; kt < kt0 + nkeys; kt += 64) {
#pragma unroll
    for (int i = 0; i < 4; ++i) {
      int c = t + 256 * i;
      int key = c >> 4, f0 = (c & 15) * 8;
      *(int4*)&Kls[key][f0] =
          *(const int4*)&kb[(kbase + kt + key) * HD + f0];
      int f = c >> 3, k0 = (c & 7) * 8;
      *(int4*)&Vt[f][k0] =
          *(const int4*)&vbT[(size_t)f * MQ + kbase + kt + k0];
    }
    __syncthreads();

    floatx4 s1[4], s2[4];
#pragma unroll
    for (int i = 0; i < 4; ++i) { s1[i] = zz; s2[i] = zz; }
#pragma unroll
    for (int ks = 0; ks < 2; ++ks)
#pragma unroll
      for (int nt = 0; nt < 4; ++nt) {
        short8 kf1 = *(const short8*)&Kls[nt * 16 + lo][ks * 32 + q8];
        short8 kf2 = *(const short8*)&Kls[nt * 16 + lo][64 + ks * 32 + q8];
        s1[nt] = __builtin_amdgcn_mfma_f32_16x16x32_bf16(qf[0][ks], kf1, s1[nt], 0, 0, 0);
        s2[nt] = __builtin_amdgcn_mfma_f32_16x16x32_bf16(qf[1][ks], kf2, s2[nt], 0, 0, 0);
      }

    // per-row tile maxes (uniform within each 16-lane group after reduce)
    float tm1[4], tm2[4];
#pragma unroll
    for (int r = 0; r < 4; ++r) {
      float a = fmaxf(fmaxf(s1[0][r], s1[1][r]), fmaxf(s1[2][r], s1[3][r]));
      float c2 = fmaxf(fmaxf(s2[0][r], s2[1][r]), fmaxf(s2[2][r], s2[3][r]));
#pragma unroll
      for (int o = 1; o < 16; o <<= 1) {
        a = fmaxf(a, __shfl_xor(a, o));
        c2 = fmaxf(c2, __shfl_xor(c2, o));
      }
      tm1[r] = a; tm2[r] = c2;
    }
    // T13 defer-max: rescale only when some row grew by >5 (wave-uniform)
    bool grow = false;
#pragma unroll
    for (int r = 0; r < 4; ++r)
      grow = grow || (tm1[r] > m1[r] + 5.f) || (tm2[r] > m2[r] + 5.f);
    if (__any(grow)) {
#pragma unroll
      for (int r = 0; r < 4; ++r) {
        float mn1 = fmaxf(m1[r], tm1[r]), mn2 = fmaxf(m2[r], tm2[r]);
        float al1 = __expf(m1[r] - mn1), al2 = __expf(m2[r] - mn2);
        m1[r] = mn1; m2[r] = mn2;
        l1[r] *= al1; l2[r] *= al2;
#pragma unroll
        for (int nt = 0; nt < 8; ++nt) { o1[nt][r] *= al1; o2[nt][r] *= al2; }
      }
    }
#pragma unroll
    for (int r = 0; r < 4; ++r) {
      float ls1 = 0.f, ls2 = 0.f;
#pragma unroll
      for (int nt = 0; nt < 4; ++nt) {
        float p1 = __expf(s1[nt][r] - m1[r]);
        float p2 = __expf(s2[nt][r] - m2[r]);
        ls1 += p1; ls2 += p2;
        Pls[w][0][quad * 4 + r][nt * 16 + lo] = f2bf(p1);
        Pls[w][1][quad * 4 + r][nt * 16 + lo] = f2bf(p2);
      }
#pragma unroll
      for (int o = 1; o < 16; o <<= 1) {
        ls1 += __shfl_xor(ls1, o);
        ls2 += __shfl_xor(ls2, o);
      }
      l1[r] += ls1;
      l2[r] += ls2;
    }

#pragma unroll
    for (int ks = 0; ks < 2; ++ks) {
      short8 p1 = *(const short8*)&Pls[w][0][lo][ks * 32 + q8];
      short8 p2 = *(const short8*)&Pls[w][1][lo][ks * 32 + q8];
#pragma unroll
      for (int nt = 0; nt < 8; ++nt) {
        short8 vf = *(const short8*)&Vt[nt * 16 + lo][ks * 32 + q8];
        o1[nt] = __builtin_amdgcn_mfma_f32_16x16x32_bf16(p1, vf, o1[nt], 0, 0, 0);
        o2[nt] = __builtin_amdgcn_mfma_f32_16x16x32_bf16(p2, vf, o2[nt], 0, 0, 0);
      }
    }
    __syncthreads();
  }

#pragma unroll
  for (int r = 0; r < 4; ++r) {
    int rowb = q0 + w * 16 + quad * 4 + r;
    size_t idx = ((size_t)(ksp * 4 + b)) * TQ + rowb;
    if (lo == 0) pstats[idx] = make_float4(m1[r], l1[r], m2[r], l2[r]);
#pragma unroll
    for (int nt = 0; nt < 8; ++nt) {
      pO1[idx * HD + nt * 16 + lo] = f2bf(o1[nt][r]);
      pO2[idx * HD + nt * 16 + lo] = f2bf(o2[nt][r]);
    }
  }
}

// ---------------------------------------------------------------- combine ----
// Stat arrays sized for KS up to 8.
__global__ __launch_bounds__(256) void attn_combine_kernel(
    const unsigned short* __restrict__ pO1, const unsigned short* __restrict__ pO2,
    const float4* __restrict__ pstats, const float* __restrict__ lam_ptr,
    float* __restrict__ out, int ksn) {
  const int t = threadIdx.x;
  const int b = blockIdx.y;
  const int row = blockIdx.x * 16 + (t >> 4);
  const int dg = t & 15;

  float m1s[8], l1s[8], m2s[8], l2s[8];
  float M1 = -1e30f, M2 = -1e30f;
  for (int s = 0; s < ksn; ++s) {
    float4 f4 = pstats[((size_t)(s * 4 + b)) * TQ + row];
    m1s[s] = f4.x; l1s[s] = f4.y; m2s[s] = f4.z; l2s[s] = f4.w;
    M1 = fmaxf(M1, f4.x); M2 = fmaxf(M2, f4.z);
  }
  float L1 = 0.f, L2 = 0.f, e1[8], e2[8];
  for (int s = 0; s < ksn; ++s) {
    e1[s] = __expf(m1s[s] - M1); e2[s] = __expf(m2s[s] - M2);
    L1 += l1s[s] * e1[s]; L2 += l2s[s] * e2[s];
  }
  float a1[8], a2[8];
#pragma unroll
  for (int j = 0; j < 8; ++j) { a1[j] = 0.f; a2[j] = 0.f; }
  for (int s = 0; s < ksn; ++s) {
    size_t base = (((size_t)(s * 4 + b)) * TQ + row) * HD + dg * 8;
    int4 r1 = *(const int4*)&pO1[base];
    int4 r2 = *(const int4*)&pO2[base];
    const unsigned short* u1 = (const unsigned short*)&r1;
    const unsigned short* u2 = (const unsigned short*)&r2;
#pragma unroll
    for (int j = 0; j < 8; ++j) {
      a1[j] += bf2f(u1[j]) * e1[s];
      a2[j] += bf2f(u2[j]) * e2[s];
    }
  }
  const float i1 = 1.f / L1;
  const float i2 = lam_ptr[0] / L2;
  float4* op = (float4*)&out[((size_t)b * TQ + row) * HD + dg * 8];
  op[0] = make_float4(a1[0] * i1 - a2[0] * i2, a1[1] * i1 - a2[1] * i2,
                      a1[2] * i1 - a2[2] * i2, a1[3] * i1 - a2[3] * i2);
  op[1] = make_float4(a1[4] * i1 - a2[4] * i2, a1[5] * i1 - a2[5] * i2,
                      a1[6] * i1 - a2[6] * i2, a1[7] * i1 - a2[7] * i2);
}

// --------------------------------------------------------------- tripwire ----
__global__ __launch_bounds__(256) void attn_check_kernel(
    const unsigned short* __restrict__ qb, const unsigned short* __restrict__ kb,
    const unsigned short* __restrict__ vbT, const float* __restrict__ lamp,
    float* __restrict__ out) {
  __shared__ float qsh[HD];
  __shared__ float sred[4][4];
  const int t = threadIdx.x;
  const int w = t >> 6, lane = t & 63;
  const int bb = blockIdx.x & 3;
  const int q = (int)((blockIdx.x * 997u + 13u) & 2047u);
  const int dc = (int)((blockIdx.x * 37u + 5u) & 127u);

  const unsigned short* qr = &qb[((size_t)bb * TQ + q) * HD];
  if (t < HD) qsh[t] = bf2f(qr[t]);
  __syncthreads();

  float mx1 = -1e30f, mx2 = -1e30f;
  for (int it = 0; it < 8; ++it) {
    int key = t + 256 * it;
    const unsigned* kr = (const unsigned*)&kb[((size_t)bb * TK + key) * HD];
    float s1 = 0.f, s2 = 0.f;
#pragma unroll 8
    for (int du = 0; du < 32; ++du) {
      unsigned u1 = kr[du], u2 = kr[32 + du];
      s1 += qsh[2 * du] * bf2f((unsigned short)u1) +
            qsh[2 * du + 1] * bf2f((unsigned short)(u1 >> 16));
      s2 += qsh[64 + 2 * du] * bf2f((unsigned short)u2) +
            qsh[64 + 2 * du + 1] * bf2f((unsigned short)(u2 >> 16));
    }
    mx1 = fmaxf(mx1, s1); mx2 = fmaxf(mx2, s2);
  }
  for (int o = 1; o < 64; o <<= 1) {
    mx1 = fmaxf(mx1, __shfl_xor(mx1, o));
    mx2 = fmaxf(mx2, __shfl_xor(mx2, o));
  }
  if (lane == 0) { sred[0][w] = mx1; sred[1][w] = mx2; }
  __syncthreads();
  mx1 = fmaxf(fmaxf(sred[0][0], sred[0][1]), fmaxf(sred[0][2], sred[0][3]));
  mx2 = fmaxf(fmaxf(sred[1][0], sred[1][1]), fmaxf(sred[1][2], sred[1][3]));
  __syncthreads();

  float l1 = 0.f, l2 = 0.f, o1 = 0.f, o2 = 0.f;
  for (int it = 0; it < 8; ++it) {
    int key = t + 256 * it;
    const unsigned* kr = (const unsigned*)&kb[((size_t)bb * TK + key) * HD];
    float s1 = 0.f, s2 = 0.f;
#pragma unroll 8
    for (int du = 0; du < 32; ++du) {
      unsigned u1 = kr[du], u2 = kr[32 + du];
      s1 += qsh[2 * du] * bf2f((unsigned short)u1) +
            qsh[2 * du + 1] * bf2f((unsigned short)(u1 >> 16));
      s2 += qsh[64 + 2 * du] * bf2f((unsigned short)u2) +
            qsh[64 + 2 * du + 1] * bf2f((unsigned short)(u2 >> 16));
    }
    float p1 = __expf(s1 - mx1), p2 = __expf(s2 - mx2);
    float v = bf2f(vbT[(size_t)dc * MQ + bb * TK + key]);
    l1 += p1; l2 += p2; o1 += p1 * v; o2 += p2 * v;
  }
  for (int o = 1; o < 64; o <<= 1) {
    l1 += __shfl_xor(l1, o); l2 += __shfl_xor(l2, o);
    o1 += __shfl_xor(o1, o); o2 += __shfl_xor(o2, o);
  }
  if (lane == 0) { sred[0][w] = l1; sred[1][w] = l2; sred[2][w] = o1; sred[3][w] = o2; }
  __syncthreads();
  if (t == 0) {
    l1 = sred[0][0] + sred[0][1] + sred[0][2] + sred[0][3];
    l2 = sred[1][0] + sred[1][1] + sred[1][2] + sred[1][3];
    o1 = sred[2][0] + sred[2][1] + sred[2][2] + sred[2][3];
    o2 = sred[3][0] + sred[3][1] + sred[3][2] + sred[3][3];
    float res = o1 / l1 - lamp[0] * (o2 / l2);
    float got = out[((size_t)bb * TQ + q) * HD + dc];
    if (!(fabsf(res - got) <= 0.02f)) out[0] = 1.0e7f;
  }
}

extern "C" void kernel_launch(void* const* d_in, const int* in_sizes, int n_in,
                              void* d_out, int out_size, void* d_ws, size_t ws_size,
                              hipStream_t stream) {
  const float* x    = (const float*)d_in[0];
  const float* enc  = (const float*)d_in[1];
  const float* Wq   = (const float*)d_in[2];
  const float* bq   = (const float*)d_in[3];
  const float* Wk   = (const float*)d_in[4];
  const float* bk   = (const float*)d_in[5];
  const float* Wv   = (const float*)d_in[6];
  const float* bv   = (const float*)d_in[7];
  const float* lq1  = (const float*)d_in[8];
  const float* lk1  = (const float*)d_in[9];
  const float* lq2  = (const float*)d_in[10];
  const float* lk2  = (const float*)d_in[11];
  const float* lini = (const float*)d_in[12];
  float* out = (float*)d_out;

  char* p = (char*)d_ws;
  float* lam = (float*)p;                       p += 256;
  unsigned short* qb  = (unsigned short*)p;     p += (size_t)MQ * HD * 2;
  unsigned short* kb  = (unsigned short*)p;     p += (size_t)MQ * HD * 2;
  unsigned short* vbT = (unsigned short*)p;     p += (size_t)MQ * HD * 2;  // [128][8192]
  unsigned short* WqT = (unsigned short*)p;     p += (size_t)EMB * HD * 2;
  unsigned short* WkT = (unsigned short*)p;     p += (size_t)EMB * HD * 2;
  unsigned short* WvT = (unsigned short*)p;     p += (size_t)EMB * HD * 2;
  const size_t base_need = (size_t)(p - (char*)d_ws);

  const size_t per_ks = (size_t)4 * TQ * 16 + 2ull * 4 * TQ * HD * 2;
  int KS = 4;
  while (KS > 1 && base_need + (size_t)KS * per_ks > ws_size) KS >>= 1;

  float4* pstats = (float4*)p;                  p += (size_t)KS * 4 * TQ * 16;
  unsigned short* pO1 = (unsigned short*)p;     p += (size_t)KS * 4 * TQ * HD * 2;
  unsigned short* pO2 = (unsigned short*)p;

  hipLaunchKernelGGL(cvtWT_kernel, dim3(512, 4), dim3(256), 0, stream,
                     Wq, Wk, Wv, WqT, WkT, WvT, lq1, lk1, lq2, lk2, lini, lam);
  hipLaunchKernelGGL(gemm_proj_kernel, dim3(MQ / 32, 3), dim3(256), 0, stream,
                     x, enc, WqT, WkT, WvT, bq, bk, bv, qb, kb, vbT);
  hipLaunchKernelGGL(attn_split_kernel, dim3(TQ / 64, 4, KS), dim3(256), 0, stream,
                     qb, kb, vbT, pO1, pO2, pstats, TK / KS);
  hipLaunchKernelGGL(attn_combine_kernel, dim3(TQ / 16, 4), dim3(256), 0, stream,
                     pO1, pO2, pstats, lam, out, KS);
  hipLaunchKernelGGL(attn_check_kernel, dim3(128), dim3(256), 0, stream,
                     qb, kb, vbT, lam, out);
}

// Round 8
// 208.994 us; speedup vs baseline: 1.1726x; 1.0307x over previous
//
#include <hip/hip_runtime.h>
#include <hip/hip_bf16.h>

// Problem: B=4, Tq=Tk=2048, E=1024, D=128, d=64. All inputs fp32, output fp32.
// Round 18: group-split attn. r17 profile: latency-bound at 2 waves/SIMD,
// VGPR pinned at the 128 cliff — restructures that ADD regs all failed
// (r12-r16). Instead halve per-wave demand: 512-thr blocks, 8 waves; waves
// 0-3 compute softmax-group 1 (q/K half 0), waves 4-7 group 2, same 64
// q-rows, shared K/V tile. Per-wave: o[8]+s[4]+qf[2] ~= 100 regs <= 128 ->
// 16 waves/CU (2 blocks) = 2x TLP; per-wave MFMA halves (24/tile) so matrix
// pipe per SIMD unchanged. __launch_bounds__(512,4) pins the 128-reg budget.
// pstats -> per-group float2 (same bytes). T13 defer-max kept per group.
// gemm_proj / cvtWT(+lam) / tripwire unchanged from r17.

#define TQ 2048
#define TK 2048
#define EMB 1024
#define HD 128
#define MQ 8192  // B*Tq rows

typedef __attribute__((ext_vector_type(8))) short short8;   // 8 bf16 = 4 VGPR
typedef __attribute__((ext_vector_type(4))) float floatx4;  // MFMA acc

__device__ __forceinline__ unsigned short f2bf(float f) {  // RNE fp32->bf16
  union { float f; unsigned u; } v; v.f = f;
  unsigned r = v.u + 0x7fffu + ((v.u >> 16) & 1u);
  return (unsigned short)(r >> 16);
}
__device__ __forceinline__ float bf2f(unsigned short s) {
  union { unsigned u; float f; } v; v.u = ((unsigned)s) << 16;
  return v.f;
}

typedef const __attribute__((address_space(1))) unsigned int guint;
typedef __attribute__((address_space(3))) unsigned int luint;
__device__ __forceinline__ void gl16(const void* g, void* l) {
  __builtin_amdgcn_global_load_lds((guint*)g, (luint*)l, 16, 0, 0);
}

// ------------------------------------- weight convert+transpose (+ lambda) ----
__global__ __launch_bounds__(256) void cvtWT_kernel(
    const float* __restrict__ Wq, const float* __restrict__ Wk,
    const float* __restrict__ Wv, unsigned short* __restrict__ WqT,
    unsigned short* __restrict__ WkT, unsigned short* __restrict__ WvT,
    const float* __restrict__ lq1, const float* __restrict__ lk1,
    const float* __restrict__ lq2, const float* __restrict__ lk2,
    const float* __restrict__ linit, float* __restrict__ lam_out) {
  const int g = blockIdx.y;
  if (g == 3) {  // lambda: one block, first wave
    if (blockIdx.x == 0 && threadIdx.x < 64) {
      int j = threadIdx.x;
      float s1 = lq1[j] * lk1[j] + lq1[j + 64] * lk1[j + 64];
      float s2 = lq2[j] * lk2[j] + lq2[j + 64] * lk2[j + 64];
      for (int off = 1; off < 64; off <<= 1) {
        s1 += __shfl_xor(s1, off);
        s2 += __shfl_xor(s2, off);
      }
      if (j == 0) lam_out[0] = __expf(s1) - __expf(s2) + linit[0];
    }
    return;
  }
  const float* W = (g == 0) ? Wq : (g == 1) ? Wk : Wv;
  unsigned short* WT = (g == 0) ? WqT : (g == 1) ? WkT : WvT;
  int idx = blockIdx.x * 256 + threadIdx.x;  // [0, 131072)
  int n = idx >> 10, k = idx & 1023;
  WT[idx] = f2bf(W[(size_t)k * HD + n]);
}

// -------------------------------------------------------- MFMA projections ----
// grid (MQ/32, 3), 256 thr (4 waves). wave w: wm=w&1 -> rows 16wm..+16,
// wn=w>>1 -> cols 64wn..+64. Per K-step (BK=64): A fp32 32x64 (8KB, 8 chunks)
// + B^T bf16 128x64 (16KB, 16 chunks) staged via global_load_lds dwordx4,
// double-buffered; 8 MFMA/wave. g=0: qb*(0.125); g=1: kb; g=2: vbT^T.
__global__ __launch_bounds__(256) void gemm_proj_kernel(
    const float* __restrict__ x, const float* __restrict__ enc,
    const unsigned short* __restrict__ WqT, const unsigned short* __restrict__ WkT,
    const unsigned short* __restrict__ WvT,
    const float* __restrict__ bq, const float* __restrict__ bk,
    const float* __restrict__ bv,
    unsigned short* __restrict__ qb, unsigned short* __restrict__ kb,
    unsigned short* __restrict__ vbT) {
  __shared__ __align__(16) float Ab[2][32 * 64];             // 16 KB, linear (no pad)
  __shared__ __align__(16) unsigned short Bb[2][128 * 64];   // 32 KB, linear (no pad)
  const int t = threadIdx.x;
  const int w = t >> 6, lane = t & 63;
  const int lo = lane & 15, quad = lane >> 4;
  const int wm = w & 1, wn = w >> 1;
  const int g = blockIdx.y;
  const size_t m0 = (size_t)blockIdx.x * 32;
  const float* A = (g == 0) ? x : enc;
  const unsigned short* BT = (g == 0) ? WqT : (g == 1) ? WkT : WvT;
  const float* bias = (g == 0) ? bq : (g == 1) ? bk : bv;

  // Per-lane staging sources, pre-swizzled so linear LDS + swizzled ds_read
  // reconstructs the original element (involution: col_byte ^= ((row&7)<<4)).
  // A: 8 chunks of 1KB (4 rows x 256B); wave w owns chunks 2w, 2w+1.
  const float* gA[2];
  int ldsAoff[2];
#pragma unroll
  for (int j = 0; j < 2; ++j) {
    int c = 2 * w + j;
    int row = 4 * c + (lane >> 4);
    int colb = ((lane & 15) * 16) ^ ((row & 7) << 4);
    gA[j] = A + (m0 + row) * EMB + (colb >> 2);
    ldsAoff[j] = c * 1024;
  }
  // B: 16 chunks of 1KB (8 rows x 128B); wave w owns chunks 4w..4w+3.
  const unsigned short* gB[4];
  int ldsBoff[4];
#pragma unroll
  for (int j = 0; j < 4; ++j) {
    int c = 4 * w + j;
    int row = 8 * c + (lane >> 3);
    int colb = ((lane & 7) * 16) ^ ((row & 7) << 4);
    gB[j] = BT + (size_t)row * EMB + (colb >> 1);
    ldsBoff[j] = c * 1024;
  }

  floatx4 acc[4];
  const floatx4 zz = {0.f, 0.f, 0.f, 0.f};
#pragma unroll
  for (int i = 0; i < 4; ++i) acc[i] = zz;

  const int xr = (lo & 7) << 4;

  auto stage = [&](int kt, int bsel) {
#pragma unroll
    for (int j = 0; j < 2; ++j) gl16(gA[j] + kt, (char*)&Ab[bsel][0] + ldsAoff[j]);
#pragma unroll
    for (int j = 0; j < 4; ++j) gl16(gB[j] + kt, (char*)&Bb[bsel][0] + ldsBoff[j]);
  };

  auto compute = [&](int bsel) {
    const char* Arow = (const char*)&Ab[bsel][(16 * wm + lo) * 64];
    const char* Bbase = (const char*)&Bb[bsel][0];
#pragma unroll
    for (int ks = 0; ks < 2; ++ks) {
      int a0 = (ks * 128 + quad * 32) ^ xr;
      float4 fa = *(const float4*)(Arow + a0);         // orig cols ks*32+q8 .. +3
      float4 fb = *(const float4*)(Arow + (a0 ^ 16));  // orig cols ks*32+q8+4 .. +7
      short8 af;
      af[0] = (short)f2bf(fa.x); af[1] = (short)f2bf(fa.y);
      af[2] = (short)f2bf(fa.z); af[3] = (short)f2bf(fa.w);
      af[4] = (short)f2bf(fb.x); af[5] = (short)f2bf(fb.y);
      af[6] = (short)f2bf(fb.z); af[7] = (short)f2bf(fb.w);
      int b0 = (ks * 64 + quad * 16) ^ xr;
#pragma unroll
      for (int nt = 0; nt < 4; ++nt) {
        int row = wn * 64 + nt * 16 + lo;
        short8 bfr = *(const short8*)(Bbase + row * 128 + b0);
        acc[nt] = __builtin_amdgcn_mfma_f32_16x16x32_bf16(af, bfr, acc[nt], 0, 0, 0);
      }
    }
  };

  // prologue: stage K-tile 0 into buf0 (syncthreads drains vmcnt+lgkmcnt)
  stage(0, 0);
  __syncthreads();

  // 2-phase pipeline, unrolled 2-deep -> static buffer indices
  for (int kt = 0; kt < EMB; kt += 128) {
    stage(kt + 64, 1);          // prefetch next tile (kt+64 <= 960, always valid)
    compute(0);                 // consume tile kt
    __syncthreads();            // drains: buf1 loads done, buf0 reads done
    if (kt + 128 < EMB) stage(kt + 128, 0);
    compute(1);                 // consume tile kt+64
    __syncthreads();
  }

  // epilogue: rows m0+16wm+quad*4+r, cols 64wn+nt*16+lo
  const int mrow = 16 * wm + quad * 4;
  if (g < 2) {
    unsigned short* Y = (g == 0) ? qb : kb;
    const float sc = (g == 0) ? 0.125f : 1.0f;
#pragma unroll
    for (int nt = 0; nt < 4; ++nt) {
      float bn = bias[wn * 64 + nt * 16 + lo];
#pragma unroll
      for (int r = 0; r < 4; ++r)
        Y[(m0 + mrow + r) * HD + wn * 64 + nt * 16 + lo] = f2bf((acc[nt][r] + bn) * sc);
    }
  } else {
#pragma unroll
    for (int nt = 0; nt < 4; ++nt) {
      float bn = bias[wn * 64 + nt * 16 + lo];
      unsigned long long pk = 0;
#pragma unroll
      for (int r = 0; r < 4; ++r)
        pk |= (unsigned long long)f2bf(acc[nt][r] + bn) << (16 * r);
      *(unsigned long long*)&vbT[(size_t)(wn * 64 + nt * 16 + lo) * MQ + m0 + mrow] = pk;
    }
  }
}

// ---------------------------------------------------- attention (key-split) ----
// Round 18: 512 thr / 8 waves. Waves 0-3: group 1 (q/K cols 0..63), waves
// 4-7: group 2 (cols 64..127); wave wv in a group owns q-rows q0+16wv..+16.
// Shared K/V tile staged by all 512 threads. Per-wave: 24 MFMA/tile,
// o[8]+s[4]+qf[2] ~= 100 VGPR <= 128 -> 16 waves/CU. T13 defer-max per group.
__global__ __launch_bounds__(512, 4) void attn_split_kernel(
    const unsigned short* __restrict__ qb, const unsigned short* __restrict__ kb,
    const unsigned short* __restrict__ vbT,
    unsigned short* __restrict__ pO1, unsigned short* __restrict__ pO2,
    float2* __restrict__ pstats, int nkeys) {
  __shared__ __align__(16) unsigned short Kls[64][136];   // 17.4 KB
  __shared__ __align__(16) unsigned short Vt[128][72];    // 18.4 KB
  __shared__ __align__(16) unsigned short Pls[8][16][72]; // 18.4 KB

  const int t = threadIdx.x;
  const int w = t >> 6;        // 0..7
  const int g = w >> 2;        // softmax group 0/1
  const int wv = w & 3;        // wave within group -> q-row block
  const int lane = t & 63;
  const int lo = lane & 15;
  const int quad = lane >> 4;
  const int q8 = quad * 8;
  const int b = blockIdx.y;
  const int q0 = blockIdx.x * 64;
  const int ksp = blockIdx.z;
  const int kt0 = ksp * nkeys;
  const int ksTot = TK / nkeys;
  const size_t kbase = (size_t)b * TK;

  const size_t qrow = (size_t)b * TQ + q0 + wv * 16 + lo;
  short8 qf[2];
#pragma unroll
  for (int ks = 0; ks < 2; ++ks)
    qf[ks] = *(const short8*)&qb[qrow * HD + g * 64 + ks * 32 + q8];

  floatx4 o[8];
  const floatx4 zz = {0.f, 0.f, 0.f, 0.f};
#pragma unroll
  for (int i = 0; i < 8; ++i) o[i] = zz;
  float m[4], l[4];
#pragma unroll
  for (int r = 0; r < 4; ++r) { m[r] = -1e30f; l[r] = 0.f; }

  for (int kt = kt0; kt < kt0 + nkeys; kt += 64) {
    // cooperative staging: 1024 K-chunks + 1024 V-chunks, 512 threads x 2 iters
#pragma unroll
    for (int i = 0; i < 2; ++i) {
      int c = t + 512 * i;
      int key = c >> 4, f0 = (c & 15) * 8;
      *(int4*)&Kls[key][f0] =
          *(const int4*)&kb[(kbase + kt + key) * HD + f0];
      int f = c >> 3, k0 = (c & 7) * 8;
      *(int4*)&Vt[f][k0] =
          *(const int4*)&vbT[(size_t)f * MQ + kbase + kt + k0];
    }
    __syncthreads();

    floatx4 s[4];
#pragma unroll
    for (int i = 0; i < 4; ++i) s[i] = zz;
#pragma unroll
    for (int ks = 0; ks < 2; ++ks)
#pragma unroll
      for (int nt = 0; nt < 4; ++nt) {
        short8 kf = *(const short8*)&Kls[nt * 16 + lo][g * 64 + ks * 32 + q8];
        s[nt] = __builtin_amdgcn_mfma_f32_16x16x32_bf16(qf[ks], kf, s[nt], 0, 0, 0);
      }

    // per-row tile maxes (uniform within 16-lane groups after reduce)
    float tm[4];
#pragma unroll
    for (int r = 0; r < 4; ++r) {
      float a = fmaxf(fmaxf(s[0][r], s[1][r]), fmaxf(s[2][r], s[3][r]));
#pragma unroll
      for (int oo = 1; oo < 16; oo <<= 1) a = fmaxf(a, __shfl_xor(a, oo));
      tm[r] = a;
    }
    // T13 defer-max: rescale only when some row grew by >5 (wave-uniform)
    bool grow = false;
#pragma unroll
    for (int r = 0; r < 4; ++r) grow = grow || (tm[r] > m[r] + 5.f);
    if (__any(grow)) {
#pragma unroll
      for (int r = 0; r < 4; ++r) {
        float mn = fmaxf(m[r], tm[r]);
        float al = __expf(m[r] - mn);
        m[r] = mn;
        l[r] *= al;
#pragma unroll
        for (int nt = 0; nt < 8; ++nt) o[nt][r] *= al;
      }
    }
#pragma unroll
    for (int r = 0; r < 4; ++r) {
      float ls = 0.f;
#pragma unroll
      for (int nt = 0; nt < 4; ++nt) {
        float p = __expf(s[nt][r] - m[r]);
        ls += p;
        Pls[w][quad * 4 + r][nt * 16 + lo] = f2bf(p);
      }
#pragma unroll
      for (int oo = 1; oo < 16; oo <<= 1) ls += __shfl_xor(ls, oo);
      l[r] += ls;
    }

#pragma unroll
    for (int ks = 0; ks < 2; ++ks) {
      short8 p8 = *(const short8*)&Pls[w][lo][ks * 32 + q8];
#pragma unroll
      for (int nt = 0; nt < 8; ++nt) {
        short8 vf = *(const short8*)&Vt[nt * 16 + lo][ks * 32 + q8];
        o[nt] = __builtin_amdgcn_mfma_f32_16x16x32_bf16(p8, vf, o[nt], 0, 0, 0);
      }
    }
    __syncthreads();
  }

  unsigned short* Y = g ? pO2 : pO1;
#pragma unroll
  for (int r = 0; r < 4; ++r) {
    int rowb = q0 + wv * 16 + quad * 4 + r;
    size_t idx = ((size_t)(ksp * 4 + b)) * TQ + rowb;
    if (lo == 0)
      pstats[((size_t)(g * ksTot + ksp) * 4 + b) * TQ + rowb] = make_float2(m[r], l[r]);
#pragma unroll
    for (int nt = 0; nt < 8; ++nt)
      Y[idx * HD + nt * 16 + lo] = f2bf(o[nt][r]);
  }
}

// ---------------------------------------------------------------- combine ----
// pstats layout: [(g*ksn + s)*4 + b)*TQ + row] -> (m, l) per group.
__global__ __launch_bounds__(256) void attn_combine_kernel(
    const unsigned short* __restrict__ pO1, const unsigned short* __restrict__ pO2,
    const float2* __restrict__ pstats, const float* __restrict__ lam_ptr,
    float* __restrict__ out, int ksn) {
  const int t = threadIdx.x;
  const int b = blockIdx.y;
  const int row = blockIdx.x * 16 + (t >> 4);
  const int dg = t & 15;

  float m1s[8], l1s[8], m2s[8], l2s[8];
  float M1 = -1e30f, M2 = -1e30f;
  for (int s = 0; s < ksn; ++s) {
    float2 fa = pstats[((size_t)(s) * 4 + b) * TQ + row];
    float2 fb = pstats[((size_t)(ksn + s) * 4 + b) * TQ + row];
    m1s[s] = fa.x; l1s[s] = fa.y; m2s[s] = fb.x; l2s[s] = fb.y;
    M1 = fmaxf(M1, fa.x); M2 = fmaxf(M2, fb.x);
  }
  float L1 = 0.f, L2 = 0.f, e1[8], e2[8];
  for (int s = 0; s < ksn; ++s) {
    e1[s] = __expf(m1s[s] - M1); e2[s] = __expf(m2s[s] - M2);
    L1 += l1s[s] * e1[s]; L2 += l2s[s] * e2[s];
  }
  float a1[8], a2[8];
#pragma unroll
  for (int j = 0; j < 8; ++j) { a1[j] = 0.f; a2[j] = 0.f; }
  for (int s = 0; s < ksn; ++s) {
    size_t base = (((size_t)(s * 4 + b)) * TQ + row) * HD + dg * 8;
    int4 r1 = *(const int4*)&pO1[base];
    int4 r2 = *(const int4*)&pO2[base];
    const unsigned short* u1 = (const unsigned short*)&r1;
    const unsigned short* u2 = (const unsigned short*)&r2;
#pragma unroll
    for (int j = 0; j < 8; ++j) {
      a1[j] += bf2f(u1[j]) * e1[s];
      a2[j] += bf2f(u2[j]) * e2[s];
    }
  }
  const float i1 = 1.f / L1;
  const float i2 = lam_ptr[0] / L2;
  float4* op = (float4*)&out[((size_t)b * TQ + row) * HD + dg * 8];
  op[0] = make_float4(a1[0] * i1 - a2[0] * i2, a1[1] * i1 - a2[1] * i2,
                      a1[2] * i1 - a2[2] * i2, a1[3] * i1 - a2[3] * i2);
  op[1] = make_float4(a1[4] * i1 - a2[4] * i2, a1[5] * i1 - a2[5] * i2,
                      a1[6] * i1 - a2[6] * i2, a1[7] * i1 - a2[7] * i2);
}

// --------------------------------------------------------------- tripwire ----
__global__ __launch_bounds__(256) void attn_check_kernel(
    const unsigned short* __restrict__ qb, const unsigned short* __restrict__ kb,
    const unsigned short* __restrict__ vbT, const float* __restrict__ lamp,
    float* __restrict__ out) {
  __shared__ float qsh[HD];
  __shared__ float sred[4][4];
  const int t = threadIdx.x;
  const int w = t >> 6, lane = t & 63;
  const int bb = blockIdx.x & 3;
  const int q = (int)((blockIdx.x * 997u + 13u) & 2047u);
  const int dc = (int)((blockIdx.x * 37u + 5u) & 127u);

  const unsigned short* qr = &qb[((size_t)bb * TQ + q) * HD];
  if (t < HD) qsh[t] = bf2f(qr[t]);
  __syncthreads();

  float mx1 = -1e30f, mx2 = -1e30f;
  for (int it = 0; it < 8; ++it) {
    int key = t + 256 * it;
    const unsigned* kr = (const unsigned*)&kb[((size_t)bb * TK + key) * HD];
    float s1 = 0.f, s2 = 0.f;
#pragma unroll 8
    for (int du = 0; du < 32; ++du) {
      unsigned u1 = kr[du], u2 = kr[32 + du];
      s1 += qsh[2 * du] * bf2f((unsigned short)u1) +
            qsh[2 * du + 1] * bf2f((unsigned short)(u1 >> 16));
      s2 += qsh[64 + 2 * du] * bf2f((unsigned short)u2) +
            qsh[64 + 2 * du + 1] * bf2f((unsigned short)(u2 >> 16));
    }
    mx1 = fmaxf(mx1, s1); mx2 = fmaxf(mx2, s2);
  }
  for (int o = 1; o < 64; o <<= 1) {
    mx1 = fmaxf(mx1, __shfl_xor(mx1, o));
    mx2 = fmaxf(mx2, __shfl_xor(mx2, o));
  }
  if (lane == 0) { sred[0][w] = mx1; sred[1][w] = mx2; }
  __syncthreads();
  mx1 = fmaxf(fmaxf(sred[0][0], sred[0][1]), fmaxf(sred[0][2], sred[0][3]));
  mx2 = fmaxf(fmaxf(sred[1][0], sred[1][1]), fmaxf(sred[1][2], sred[1][3]));
  __syncthreads();

  float l1 = 0.f, l2 = 0.f, o1 = 0.f, o2 = 0.f;
  for (int it = 0; it < 8; ++it) {
    int key = t + 256 * it;
    const unsigned* kr = (const unsigned*)&kb[((size_t)bb * TK + key) * HD];
    float s1 = 0.f, s2 = 0.f;
#pragma unroll 8
    for (int du = 0; du < 32; ++du) {
      unsigned u1 = kr[du], u2 = kr[32 + du];
      s1 += qsh[2 * du] * bf2f((unsigned short)u1) +
            qsh[2 * du + 1] * bf2f((unsigned short)(u1 >> 16));
      s2 += qsh[64 + 2 * du] * bf2f((unsigned short)u2) +
            qsh[64 + 2 * du + 1] * bf2f((unsigned short)(u2 >> 16));
    }
    float p1 = __expf(s1 - mx1), p2 = __expf(s2 - mx2);
    float v = bf2f(vbT[(size_t)dc * MQ + bb * TK + key]);
    l1 += p1; l2 += p2; o1 += p1 * v; o2 += p2 * v;
  }
  for (int o = 1; o < 64; o <<= 1) {
    l1 += __shfl_xor(l1, o); l2 += __shfl_xor(l2, o);
    o1 += __shfl_xor(o1, o); o2 += __shfl_xor(o2, o);
  }
  if (lane == 0) { sred[0][w] = l1; sred[1][w] = l2; sred[2][w] = o1; sred[3][w] = o2; }
  __syncthreads();
  if (t == 0) {
    l1 = sred[0][0] + sred[0][1] + sred[0][2] + sred[0][3];
    l2 = sred[1][0] + sred[1][1] + sred[1][2] + sred[1][3];
    o1 = sred[2][0] + sred[2][1] + sred[2][2] + sred[2][3];
    o2 = sred[3][0] + sred[3][1] + sred[3][2] + sred[3][3];
    float res = o1 / l1 - lamp[0] * (o2 / l2);
    float got = out[((size_t)bb * TQ + q) * HD + dc];
    if (!(fabsf(res - got) <= 0.02f)) out[0] = 1.0e7f;
  }
}

extern "C" void kernel_launch(void* const* d_in, const int* in_sizes, int n_in,
                              void* d_out, int out_size, void* d_ws, size_t ws_size,
                              hipStream_t stream) {
  const float* x    = (const float*)d_in[0];
  const float* enc  = (const float*)d_in[1];
  const float* Wq   = (const float*)d_in[2];
  const float* bq   = (const float*)d_in[3];
  const float* Wk   = (const float*)d_in[4];
  const float* bk   = (const float*)d_in[5];
  const float* Wv   = (const float*)d_in[6];
  const float* bv   = (const float*)d_in[7];
  const float* lq1  = (const float*)d_in[8];
  const float* lk1  = (const float*)d_in[9];
  const float* lq2  = (const float*)d_in[10];
  const float* lk2  = (const float*)d_in[11];
  const float* lini = (const float*)d_in[12];
  float* out = (float*)d_out;

  char* p = (char*)d_ws;
  float* lam = (float*)p;                       p += 256;
  unsigned short* qb  = (unsigned short*)p;     p += (size_t)MQ * HD * 2;
  unsigned short* kb  = (unsigned short*)p;     p += (size_t)MQ * HD * 2;
  unsigned short* vbT = (unsigned short*)p;     p += (size_t)MQ * HD * 2;  // [128][8192]
  unsigned short* WqT = (unsigned short*)p;     p += (size_t)EMB * HD * 2;
  unsigned short* WkT = (unsigned short*)p;     p += (size_t)EMB * HD * 2;
  unsigned short* WvT = (unsigned short*)p;     p += (size_t)EMB * HD * 2;
  const size_t base_need = (size_t)(p - (char*)d_ws);

  // per-KS: stats 2 groups x 4 x TQ x sizeof(float2) (= 4*TQ*16) + pO1/pO2
  const size_t per_ks = (size_t)4 * TQ * 16 + 2ull * 4 * TQ * HD * 2;
  int KS = 4;
  while (KS > 1 && base_need + (size_t)KS * per_ks > ws_size) KS >>= 1;

  float2* pstats = (float2*)p;                  p += (size_t)KS * 4 * TQ * 16;
  unsigned short* pO1 = (unsigned short*)p;     p += (size_t)KS * 4 * TQ * HD * 2;
  unsigned short* pO2 = (unsigned short*)p;

  hipLaunchKernelGGL(cvtWT_kernel, dim3(512, 4), dim3(256), 0, stream,
                     Wq, Wk, Wv, WqT, WkT, WvT, lq1, lk1, lq2, lk2, lini, lam);
  hipLaunchKernelGGL(gemm_proj_kernel, dim3(MQ / 32, 3), dim3(256), 0, stream,
                     x, enc, WqT, WkT, WvT, bq, bk, bv, qb, kb, vbT);
  hipLaunchKernelGGL(attn_split_kernel, dim3(TQ / 64, 4, KS), dim3(512), 0, stream,
                     qb, kb, vbT, pO1, pO2, pstats, TK / KS);
  hipLaunchKernelGGL(attn_combine_kernel, dim3(TQ / 16, 4), dim3(256), 0, stream,
                     pO1, pO2, pstats, lam, out, KS);
  hipLaunchKernelGGL(attn_check_kernel, dim3(128), dim3(256), 0, stream,
                     qb, kb, vbT, lam, out);
}